// Round 10
// baseline (1009.692 us; speedup 1.0000x reference)
//
#include <hip/hip_runtime.h>
#include <hip/hip_bf16.h>

// MoE forward, B=4096 E=8 D=1024 H=4096 O=1024, fp32 in/out, bf16 MFMA compute.
//
// out = sum_e p[b,e] * (relu(x @ W1[e] + b1[e]) @ W2[e] + b2[e])
//     = (h' @ W2flat) + sum_e p[b,e]*b2[e]      with h'[b, e*H+h] = p[b,e]*relu(...)
//
// GEMM: 256x256 tile, BK=64, 512 thr (8 waves 2Mx4N), 128KB LDS dbuf, 3-bit
// row-XOR swizzle (lane-constant XOR form), 2-deep staging (same WAR-proven
// dataflow as r6/r8) but MINIMAL barriers (3/K-tile: B-consumed, A-consumed,
// vmcnt-certify) and NO manual lgkm waits -> compiler fine-grained counting
// interleaves reads under MFMA. Hoisted addressing (4 LDS base ptrs + imm
// offsets; 8 persistent global stage ptrs advanced +128B/tile).

#define B_DIM 4096
#define E_DIM 8
#define D_DIM 1024
#define H_DIM 4096
#define O_DIM 1024
#define KTOT  (E_DIM * H_DIM)   // 32768
#define KSPLIT 4

typedef __attribute__((ext_vector_type(8))) short bf16x8;
typedef __attribute__((ext_vector_type(4))) float f32x4;

__device__ __forceinline__ unsigned short f2bf(float f) {
  union { float f; unsigned u; } c; c.f = f;
  unsigned r = c.u + 0x7fffu + ((c.u >> 16) & 1u);  // RNE
  return (unsigned short)(r >> 16);
}

__device__ __forceinline__ void gload_lds16(const void* g, void* l) {
  __builtin_amdgcn_global_load_lds(
      (const __attribute__((address_space(1))) void*)g,
      (__attribute__((address_space(3))) void*)l, 16, 0, 0);
}

__device__ __forceinline__ void barfence() {
  asm volatile("" ::: "memory");
  __builtin_amdgcn_s_barrier();
  asm volatile("" ::: "memory");
}

// full-offset swizzle (used in epilogue repack; involution, conflict-spreading)
__device__ __forceinline__ unsigned swzA(unsigned o) {
  return o ^ (((o >> 7) & 7u) << 4);
}

struct StagePtrs { const char *b0a, *b0b, *b1a, *b1b, *a0a, *a0b, *a1a, *a1b; };

__device__ __forceinline__ void stage8(StagePtrs& sp, char* smem, int bufOff, unsigned dstT) {
  char* d = smem + bufOff + dstT;
  gload_lds16(sp.b0a, d + 2 * 16384);        sp.b0a += 128;
  gload_lds16(sp.b0b, d + 2 * 16384 + 8192); sp.b0b += 128;
  gload_lds16(sp.b1a, d + 3 * 16384);        sp.b1a += 128;
  gload_lds16(sp.b1b, d + 3 * 16384 + 8192); sp.b1b += 128;
  gload_lds16(sp.a0a, d + 0);                sp.a0a += 128;
  gload_lds16(sp.a0b, d + 8192);             sp.a0b += 128;
  gload_lds16(sp.a1a, d + 16384);            sp.a1a += 128;
  gload_lds16(sp.a1b, d + 16384 + 8192);     sp.a1b += 128;
}

// ---- one K-tile: quadrants q00,q01 | BAR | q11 (+stage B) | BAR | (+stage A, vmcnt) q10 ----
template<bool STAGE, int VMN>
__device__ __forceinline__ void tileK(
    char* smem, int bufOff, unsigned aRel, unsigned bRel,
    StagePtrs& sp, unsigned dstT, f32x4 (&acc)[8][4])
{
  const char* pA0 = smem + bufOff + aRel;                 // kk=0
  const char* pA1 = (const char*)((uintptr_t)pA0 ^ 64);   // kk=1 (bit-6 flip)
  const char* pB0 = smem + bufOff + bRel;
  const char* pB1 = (const char*)((uintptr_t)pB0 ^ 64);

  bf16x8 aL0[4], aL1[4], aH0[4], aH1[4], bL0[2], bL1[2], bH0[2], bH1[2];

  // q00: aLo x bLo
  #pragma unroll
  for (int m = 0; m < 4; ++m) {
    aL0[m] = *(const bf16x8*)(pA0 + m * 2048);
    aL1[m] = *(const bf16x8*)(pA1 + m * 2048);
  }
  #pragma unroll
  for (int n = 0; n < 2; ++n) {
    bL0[n] = *(const bf16x8*)(pB0 + n * 2048);
    bL1[n] = *(const bf16x8*)(pB1 + n * 2048);
  }
  __builtin_amdgcn_s_setprio(1);
  #pragma unroll
  for (int m = 0; m < 4; ++m)
    #pragma unroll
    for (int n = 0; n < 2; ++n) {
      acc[m][n] = __builtin_amdgcn_mfma_f32_16x16x32_bf16(aL0[m], bL0[n], acc[m][n], 0, 0, 0);
      acc[m][n] = __builtin_amdgcn_mfma_f32_16x16x32_bf16(aL1[m], bL1[n], acc[m][n], 0, 0, 0);
    }
  __builtin_amdgcn_s_setprio(0);

  // q01: aLo x bHi
  #pragma unroll
  for (int n = 0; n < 2; ++n) {
    bH0[n] = *(const bf16x8*)(pB0 + (2 + n) * 2048);
    bH1[n] = *(const bf16x8*)(pB1 + (2 + n) * 2048);
  }
  __builtin_amdgcn_s_setprio(1);
  #pragma unroll
  for (int m = 0; m < 4; ++m)
    #pragma unroll
    for (int n = 0; n < 2; ++n) {
      acc[m][2 + n] = __builtin_amdgcn_mfma_f32_16x16x32_bf16(aL0[m], bH0[n], acc[m][2 + n], 0, 0, 0);
      acc[m][2 + n] = __builtin_amdgcn_mfma_f32_16x16x32_bf16(aL1[m], bH1[n], acc[m][2 + n], 0, 0, 0);
    }
  __builtin_amdgcn_s_setprio(0);
  barfence();   // all waves' B reads (bLo,bHi) drained -> safe to stage B into this buf

  // q11: aHi x bHi  (+ stage next-next B)
  #pragma unroll
  for (int m = 0; m < 4; ++m) {
    aH0[m] = *(const bf16x8*)(pA0 + (4 + m) * 2048);
    aH1[m] = *(const bf16x8*)(pA1 + (4 + m) * 2048);
  }
  if (STAGE) {
    char* d = smem + bufOff + dstT;
    gload_lds16(sp.b0a, d + 2 * 16384);        sp.b0a += 128;
    gload_lds16(sp.b0b, d + 2 * 16384 + 8192); sp.b0b += 128;
    gload_lds16(sp.b1a, d + 3 * 16384);        sp.b1a += 128;
    gload_lds16(sp.b1b, d + 3 * 16384 + 8192); sp.b1b += 128;
  }
  __builtin_amdgcn_s_setprio(1);
  #pragma unroll
  for (int m = 0; m < 4; ++m)
    #pragma unroll
    for (int n = 0; n < 2; ++n) {
      acc[4 + m][2 + n] = __builtin_amdgcn_mfma_f32_16x16x32_bf16(aH0[m], bH0[n], acc[4 + m][2 + n], 0, 0, 0);
      acc[4 + m][2 + n] = __builtin_amdgcn_mfma_f32_16x16x32_bf16(aH1[m], bH1[n], acc[4 + m][2 + n], 0, 0, 0);
    }
  __builtin_amdgcn_s_setprio(0);
  barfence();   // all waves' A reads drained -> safe to stage A into this buf

  // q10: aHi x bLo  (+ stage next-next A, certify next buf)
  if (STAGE) {
    char* d = smem + bufOff + dstT;
    gload_lds16(sp.a0a, d + 0);                sp.a0a += 128;
    gload_lds16(sp.a0b, d + 8192);             sp.a0b += 128;
    gload_lds16(sp.a1a, d + 16384);            sp.a1a += 128;
    gload_lds16(sp.a1b, d + 16384 + 8192);     sp.a1b += 128;
  }
  if (VMN == 8)      { asm volatile("s_waitcnt vmcnt(8)" ::: "memory"); barfence(); }
  else if (VMN == 0) { asm volatile("s_waitcnt vmcnt(0)" ::: "memory"); barfence(); }
  __builtin_amdgcn_s_setprio(1);
  #pragma unroll
  for (int m = 0; m < 4; ++m)
    #pragma unroll
    for (int n = 0; n < 2; ++n) {
      acc[4 + m][n] = __builtin_amdgcn_mfma_f32_16x16x32_bf16(aH0[m], bL0[n], acc[4 + m][n], 0, 0, 0);
      acc[4 + m][n] = __builtin_amdgcn_mfma_f32_16x16x32_bf16(aH1[m], bL1[n], acc[4 + m][n], 0, 0, 0);
    }
  __builtin_amdgcn_s_setprio(0);
}

// ---------------- 256x256 GEMM  C = A[M,K] * Bt[N,K]^T ----------------
// MODE 1: Cout = bf16( relu(acc + b1[col]) * probs[row, col>>12] ), N=32768
// MODE 2: fp32 partial write to Cout + blockIdx.y*M*N (split-K), N=1024
template<int MODE>
__global__ __launch_bounds__(512, 2)
void gemm8p(const unsigned short* __restrict__ A,
            const unsigned short* __restrict__ Bt,
            void* __restrict__ Cout,
            const float* __restrict__ probs,
            const float* __restrict__ bias,
            int M, int N, int K, int kChunk)
{
  __shared__ __align__(128) char smem[131072];  // 2 buf x (A0,A1,B0,B1) x 16KB

  const int tid = threadIdx.x;
  const int wave = tid >> 6, lane = tid & 63;
  const int wm = wave >> 2, wn = wave & 3;

  int mt, nt, kBeg;
  if (MODE == 1) {
    int bid = blockIdx.x;
    int xcd = bid & 7, seq = bid >> 3;
    int grp = seq >> 4, g = seq & 15;
    mt = (grp & 3) * 4 + (g & 3);
    nt = xcd * 16 + (grp >> 2) * 4 + (g >> 2);
    kBeg = 0;
  } else {
    int x = blockIdx.x;
    mt = (x & 7) * 2 + ((x >> 3) & 1);
    nt = x >> 4;
    kBeg = blockIdx.y * kChunk;
  }

  const char* AbC = (const char*)(A + (size_t)mt * 256 * K);
  const char* BbC = (const char*)(Bt + (size_t)nt * 256 * K);
  const size_t rb = (size_t)K * 2;

  f32x4 acc[8][4] = {};

  // ---- hoisted LDS read addressing: swz is a lane-constant XOR on bits 4-6 ----
  const unsigned swzC = (lane & 7u) << 4;
  const unsigned slotX = (((unsigned)(lane >> 4)) * 16) ^ swzC;   // kk=0 low bits
  const unsigned aRel = (unsigned)(wm * 16384 + (lane & 15) * 128) + slotX;
  const unsigned bRel = (unsigned)((2 + (wn >> 1)) * 16384 +
                                   ((wn & 1) * 64 + (lane & 15)) * 128) + slotX;
  const unsigned dstT = (unsigned)(tid * 16);

  // ---- hoisted staging source pointers (pre-inverse-swizzled rows) ----
  const unsigned Cs = (((unsigned)(tid >> 3)) & 7u) << 4;
  const unsigned q0 = ((unsigned)(tid * 16)) ^ Cs;
  StagePtrs sp;
  {
    const char* bA = AbC + (size_t)kBeg * 2 + (size_t)(q0 >> 7) * rb + (q0 & 127);
    const char* bB = BbC + (size_t)kBeg * 2 + (size_t)(q0 >> 7) * rb + (q0 & 127);
    sp.a0a = bA;            sp.a0b = bA + 64 * rb;
    sp.a1a = bA + 128 * rb; sp.a1b = bA + 192 * rb;
    sp.b0a = bB;            sp.b0b = bB + 64 * rb;
    sp.b1a = bB + 128 * rb; sp.b1b = bB + 192 * rb;
  }

  const int NT = kChunk / 64;   // >= 3

  // prologue: tile0 -> buf0, tile1 -> buf1
  stage8(sp, smem, 0, dstT);
  stage8(sp, smem, 65536, dstT);
  asm volatile("s_waitcnt vmcnt(8)" ::: "memory");  // tile0 landed
  barfence();

  for (int t = 0; t < NT - 2; ++t)
    tileK<true, 8>(smem, (t & 1) * 65536, aRel, bRel, sp, dstT, acc);
  tileK<false, 0>(smem, ((NT - 2) & 1) * 65536, aRel, bRel, sp, dstT, acc);
  tileK<false, -1>(smem, ((NT - 1) & 1) * 65536, aRel, bRel, sp, dstT, acc);

  // epilogue: C/D layout col = lane&15, row = (lane>>4)*4 + j  [m89-verified]
  const int colBase = nt * 256 + wn * 64;
  const int rowBase = mt * 256 + wm * 128;

  if (MODE == 1) {
    // Repack wave's 128x64 bf16 sub-tile via private LDS seg (swizzled offsets),
    // then 16B coalesced stores (8 lanes x 16B = 128B contiguous per C row).
    char* myseg = smem + wave * 16384;
    const int eIdx = colBase >> 12;      // expert id (wave-uniform)
    #pragma unroll
    for (int m = 0; m < 8; ++m) {
      #pragma unroll
      for (int n = 0; n < 4; ++n) {
        const int col = colBase + n * 16 + (lane & 15);
        const float bv = bias[col];
        #pragma unroll
        for (int j = 0; j < 4; ++j) {
          const int row = rowBase + m * 16 + ((lane >> 4) * 4) + j;
          float v = acc[m][n][j] + bv;
          v = fmaxf(v, 0.0f) * probs[row * E_DIM + eIdx];
          unsigned off = (unsigned)((m * 16 + ((lane >> 4) * 4) + j) * 128 +
                                    (n * 16 + (lane & 15)) * 2);
          *(unsigned short*)(myseg + swzA(off)) = f2bf(v);
        }
      }
    }
    unsigned short* Cw = (unsigned short*)Cout;
    const int lc = (lane & 7) * 8;          // 8 bf16 = 16B per lane
    #pragma unroll
    for (int i = 0; i < 16; ++i) {
      int lr = i * 8 + (lane >> 3);         // 0..127
      bf16x8 vv = *(const bf16x8*)(myseg + swzA((unsigned)(lr * 128 + lc * 2)));
      *(bf16x8*)(&Cw[(size_t)(rowBase + lr) * N + colBase + lc]) = vv;
    }
  } else {
    float* dst = (float*)Cout + (size_t)blockIdx.y * M * N;
    #pragma unroll
    for (int m = 0; m < 8; ++m) {
      #pragma unroll
      for (int n = 0; n < 4; ++n) {
        const int col = colBase + n * 16 + (lane & 15);
        #pragma unroll
        for (int j = 0; j < 4; ++j) {
          const int row = rowBase + m * 16 + ((lane >> 4) * 4) + j;
          dst[(size_t)row * N + col] = acc[m][n][j];
        }
      }
    }
  }
}

// ---------------- gating: probs[b,e] = softmax(x @ Wg + bg) ----------------
__global__ __launch_bounds__(256) void gating_kernel(
    const float* __restrict__ x, const float* __restrict__ Wg,
    const float* __restrict__ bg, float* __restrict__ probs)
{
  __shared__ float sWg[D_DIM * E_DIM];  // 32 KB
  for (int i = threadIdx.x; i < D_DIM * E_DIM; i += 256) sWg[i] = Wg[i];
  __syncthreads();

  const int wave = threadIdx.x >> 6, lane = threadIdx.x & 63;
  const int b = blockIdx.x * 4 + wave;

  float acc[E_DIM] = {};
  const float* xr = x + (size_t)b * D_DIM;
  #pragma unroll
  for (int i = 0; i < D_DIM / 64; ++i) {
    int d = i * 64 + lane;
    float xv = xr[d];
    #pragma unroll
    for (int e = 0; e < E_DIM; ++e) acc[e] += xv * sWg[d * E_DIM + e];
  }
  #pragma unroll
  for (int e = 0; e < E_DIM; ++e) {
    #pragma unroll
    for (int off = 32; off > 0; off >>= 1) acc[e] += __shfl_down(acc[e], off);
  }
  if (lane == 0) {
    float m = -1e30f;
    #pragma unroll
    for (int e = 0; e < E_DIM; ++e) { acc[e] += bg[e]; m = fmaxf(m, acc[e]); }
    float p[E_DIM]; float s = 0.f;
    #pragma unroll
    for (int e = 0; e < E_DIM; ++e) { p[e] = expf(acc[e] - m); s += p[e]; }
    float inv = 1.0f / s;
    #pragma unroll
    for (int e = 0; e < E_DIM; ++e) probs[(size_t)b * E_DIM + e] = p[e] * inv;
  }
}

// ---------------- x (fp32) -> xb (bf16), same layout ----------------
__global__ __launch_bounds__(256) void convert_x_kernel(
    const float* __restrict__ x, unsigned short* __restrict__ xb)
{
  int i = blockIdx.x * 256 + threadIdx.x;  // one float4 per thread
  const float4* src = (const float4*)x;
  float4 v = src[i];
  union { unsigned short u[4]; unsigned long long q; } o;
  o.u[0] = f2bf(v.x); o.u[1] = f2bf(v.y); o.u[2] = f2bf(v.z); o.u[3] = f2bf(v.w);
  *(unsigned long long*)(xb + (size_t)i * 4) = o.q;
}

// ---------------- generic 64x64 transpose+convert (vectorized) ----------------
__global__ __launch_bounds__(256) void transpose_cvt(
    const float* __restrict__ src, unsigned short* __restrict__ dst,
    int ldSrc, int ldDst, size_t srcPlane, size_t dstPlane)
{
  __shared__ float t[64][65];
  const int e = blockIdx.z;
  const int x0 = blockIdx.x * 64;
  const int y0 = blockIdx.y * 64;
  const float* s = src + (size_t)e * srcPlane;
  unsigned short* d = dst + (size_t)e * dstPlane;

  const int rr = threadIdx.x >> 4;          // 0..15
  const int cc = (threadIdx.x & 15) * 4;    // 0..60
  #pragma unroll
  for (int i = 0; i < 4; ++i) {
    int r = rr + 16 * i;
    float4 v = *(const float4*)&s[(size_t)(x0 + r) * ldSrc + y0 + cc];
    t[r][cc] = v.x; t[r][cc + 1] = v.y; t[r][cc + 2] = v.z; t[r][cc + 3] = v.w;
  }
  __syncthreads();

  const int x4 = (threadIdx.x & 15) * 4;
  const int yb = threadIdx.x >> 4;
  #pragma unroll
  for (int j = 0; j < 4; ++j) {
    int y = yb + 16 * j;
    union { unsigned short u[4]; unsigned long long q; } o;
    #pragma unroll
    for (int q = 0; q < 4; ++q) o.u[q] = f2bf(t[x4 + q][y]);
    *(unsigned long long*)(d + (size_t)(y0 + y) * ldDst + x0 + x4) = o.q;
  }
}

// ---------------- reduce split-K partials + bias correction ----------------
__global__ __launch_bounds__(256) void reduce_out(
    const float* __restrict__ partial, const float* __restrict__ probs,
    const float* __restrict__ b2, float* __restrict__ out)
{
  const int i = blockIdx.x * 256 + threadIdx.x;        // over B*O/4 float4s
  const int row = i >> 8;
  const int colv = i & 255;
  const size_t plane = (size_t)B_DIM * O_DIM / 4;

  float4 v = make_float4(0.f, 0.f, 0.f, 0.f);
  #pragma unroll
  for (int ks = 0; ks < KSPLIT; ++ks) {
    float4 p = ((const float4*)partial)[ks * plane + i];
    v.x += p.x; v.y += p.y; v.z += p.z; v.w += p.w;
  }
  #pragma unroll
  for (int e = 0; e < E_DIM; ++e) {
    float pe = probs[row * E_DIM + e];
    float4 b = ((const float4*)b2)[e * (O_DIM / 4) + colv];
    v.x += pe * b.x; v.y += pe * b.y; v.z += pe * b.z; v.w += pe * b.w;
  }
  ((float4*)out)[i] = v;
}

extern "C" void kernel_launch(void* const* d_in, const int* in_sizes, int n_in,
                              void* d_out, int out_size, void* d_ws, size_t ws_size,
                              hipStream_t stream)
{
  const float* x  = (const float*)d_in[0];
  const float* W1 = (const float*)d_in[1];
  const float* b1 = (const float*)d_in[2];
  const float* W2 = (const float*)d_in[3];
  const float* b2 = (const float*)d_in[4];
  const float* Wg = (const float*)d_in[5];
  const float* bg = (const float*)d_in[6];
  float* out = (float*)d_out;

  char* ws = (char*)d_ws;
  float*          probs = (float*)ws;                                   // 128 KB
  unsigned short* xb    = (unsigned short*)(ws + (1u << 17));           // 8 MB
  unsigned short* W1t   = (unsigned short*)(ws + (1u << 17) + (8u << 20));       // 64 MB
  unsigned short* W2t   = (unsigned short*)(ws + (1u << 17) + (8u << 20) + (64u << 20)); // 64 MB
  unsigned short* hp    = (unsigned short*)(ws + (1u << 17) + (8u << 20) + (128u << 20)); // 256 MB
  float* partial = (float*)W1t;  // split-K partials alias W1t (dead after GEMM1)

  gating_kernel<<<B_DIM / 4, 256, 0, stream>>>(x, Wg, bg, probs);
  convert_x_kernel<<<(B_DIM * D_DIM / 4) / 256, 256, 0, stream>>>(x, xb);
  transpose_cvt<<<dim3(D_DIM / 64, H_DIM / 64, E_DIM), 256, 0, stream>>>(
      W1, W1t, H_DIM, D_DIM, (size_t)D_DIM * H_DIM, (size_t)H_DIM * D_DIM);
  transpose_cvt<<<dim3(H_DIM / 64, O_DIM / 64, E_DIM), 256, 0, stream>>>(
      W2, W2t, O_DIM, KTOT, (size_t)H_DIM * O_DIM, (size_t)H_DIM);

  // GEMM1: h' = bf16(p * relu(x @ W1 + b1))   M=4096 N=32768 K=1024
  gemm8p<1><<<dim3((B_DIM / 256) * (KTOT / 256), 1), 512, 0, stream>>>(
      xb, W1t, hp, probs, b1, B_DIM, KTOT, D_DIM, D_DIM);

  // GEMM2: partial[ks] = h' @ W2 (chunk ks)    M=4096 N=1024 K=32768, split-K=4
  gemm8p<2><<<dim3((B_DIM / 256) * (O_DIM / 256), KSPLIT), 512, 0, stream>>>(
      hp, W2t, partial, probs, nullptr, B_DIM, O_DIM, KTOT, KTOT / KSPLIT);

  // reduce partials + sum_e p*b2 -> out
  reduce_out<<<(B_DIM * O_DIM / 4) / 256, 256, 0, stream>>>(partial, probs, b2, out);
}